// Round 3
// baseline (673.553 us; speedup 1.0000x reference)
//
#include <hip/hip_runtime.h>
#include <hip/hip_bf16.h>

#define M_NODES 100000
#define N_EDGES 1600000
#define K_IN 512
#define N_OUT 256

typedef short bf16x8 __attribute__((ext_vector_type(8)));
typedef float f32x4 __attribute__((ext_vector_type(4)));

#define GLOBAL_AS __attribute__((address_space(1)))
#define LDS_AS __attribute__((address_space(3)))

__device__ inline unsigned short f2bf_u(float f) {
  union { float f; unsigned u; } x; x.f = f;
  unsigned r = x.u + 0x7FFFu + ((x.u >> 16) & 1u);
  return (unsigned short)(r >> 16);
}
__device__ inline float bfu2f(unsigned short h) {
  union { unsigned u; float f; } x; x.u = ((unsigned)h) << 16;
  return x.f;
}

// weight [512][256] f32 -> Wt bf16 [256][512] (transposed: B-frag k-contiguous)
__global__ void prep_w_kernel(const float* __restrict__ w, short* __restrict__ wt) {
  int idx = blockIdx.x * 256 + threadIdx.x;   // 131072 total
  int k = idx >> 8, n = idx & 255;
  wt[n * K_IN + k] = (short)f2bf_u(w[idx]);
}

// row_ptr[r] = lower_bound(row, r) over sorted row[] (COO -> CSR)
__global__ void build_rp_kernel(const int* __restrict__ row, int* __restrict__ rp) {
  int r = blockIdx.x * 256 + threadIdx.x;
  if (r > M_NODES) return;
  int lo = 0, hi = N_EDGES;
  while (lo < hi) {
    int mid = (lo + hi) >> 1;
    if (row[mid] < r) lo = mid + 1; else hi = mid;
  }
  rp[r] = lo;
}

// H = bf16(tanh(A @ W)). A fp32 [M,512], Wt bf16 [256][512].
// Block: 256 thr (4 waves), M_TILE=128 (32 rows/wave -> each B-frag feeds 2 MFMA),
// N=256, BK=64. LDS XOR-swizzled in 16B chunks: [r][k] at r*64 + ((k/8)^(r&7))*8.
__global__ __launch_bounds__(256) void gemm_tanh_kernel(
    const float* __restrict__ A, const short* __restrict__ Wt,
    unsigned short* __restrict__ H) {
  __shared__ __align__(16) short As[128 * 64];   // 16KB
  __shared__ __align__(16) short Bs[256 * 64];   // 32KB
  const int tid = threadIdx.x;
  const int wave = tid >> 6, lane = tid & 63;
  const int quad = lane >> 4, l16 = lane & 15;
  const int row0 = blockIdx.x * 128;

  f32x4 acc[2][16];
  #pragma unroll
  for (int g = 0; g < 2; ++g)
    #pragma unroll
    for (int i = 0; i < 16; ++i) acc[g][i] = (f32x4){0.f, 0.f, 0.f, 0.f};

  const int ra = tid >> 1;             // 0..127 : A tile row
  const int kh = (tid & 1) << 5;       // 0 or 32 : k offset (floats)
  const int gr = min(row0 + ra, M_NODES - 1);
  const float* Arow = A + (size_t)gr * K_IN;

  for (int k0 = 0; k0 < K_IN; k0 += 64) {
    // --- B: async global->LDS, swizzled. wave covers n in [64*wave, 64*wave+64)
    #pragma unroll
    for (int it = 0; it < 8; ++it) {
      int g = wave * 512 + it * 64 + lane;     // chunk id in Bs
      int n = g >> 3, phys = g & 7;
      int j = phys ^ (n & 7);                  // logical k-chunk
      const short* gp = Wt + (size_t)n * K_IN + k0 + j * 8;
      __builtin_amdgcn_global_load_lds(
          (GLOBAL_AS const void*)gp,
          (LDS_AS void*)&Bs[(wave * 512 + it * 64) * 8],
          16, 0, 0);
    }
    // --- A: 32 floats/thread -> bf16, swizzled chunk writes (two halves, low reg)
    #pragma unroll
    for (int half = 0; half < 2; ++half) {
      const float* p = &Arow[k0 + kh + half * 16];
      float4 b0 = *(const float4*)(p);
      float4 b1 = *(const float4*)(p + 4);
      float4 b2 = *(const float4*)(p + 8);
      float4 b3 = *(const float4*)(p + 12);
      union { unsigned short s[16]; int4 v[2]; } u;
      u.s[0]=f2bf_u(b0.x); u.s[1]=f2bf_u(b0.y); u.s[2]=f2bf_u(b0.z); u.s[3]=f2bf_u(b0.w);
      u.s[4]=f2bf_u(b1.x); u.s[5]=f2bf_u(b1.y); u.s[6]=f2bf_u(b1.z); u.s[7]=f2bf_u(b1.w);
      u.s[8]=f2bf_u(b2.x); u.s[9]=f2bf_u(b2.y); u.s[10]=f2bf_u(b2.z); u.s[11]=f2bf_u(b2.w);
      u.s[12]=f2bf_u(b3.x); u.s[13]=f2bf_u(b3.y); u.s[14]=f2bf_u(b3.z); u.s[15]=f2bf_u(b3.w);
      int lc0 = (kh + half * 16) >> 3;
      #pragma unroll
      for (int c = 0; c < 2; ++c) {
        int phys = (lc0 + c) ^ (ra & 7);
        *(int4*)&As[ra * 64 + phys * 8] = u.v[c];
      }
    }
    __syncthreads();
    // --- MFMA: A-frag m=l16(+16), k=quad*8+j ; B-frag n=l16, k=quad*8+j
    const int m0 = wave * 32 + l16;
    const int m1 = m0 + 16;
    #pragma unroll
    for (int kstep = 0; kstep < 2; ++kstep) {
      int lc = kstep * 4 + quad;
      bf16x8 af0 = *(const bf16x8*)&As[m0 * 64 + (lc ^ (m0 & 7)) * 8];
      bf16x8 af1 = *(const bf16x8*)&As[m1 * 64 + (lc ^ (m1 & 7)) * 8];
      #pragma unroll
      for (int nt = 0; nt < 16; ++nt) {
        int n = nt * 16 + l16;
        bf16x8 bfr = *(const bf16x8*)&Bs[n * 64 + (lc ^ (n & 7)) * 8];
        acc[0][nt] = __builtin_amdgcn_mfma_f32_16x16x32_bf16(af0, bfr, acc[0][nt], 0, 0, 0);
        acc[1][nt] = __builtin_amdgcn_mfma_f32_16x16x32_bf16(af1, bfr, acc[1][nt], 0, 0, 0);
      }
    }
    __syncthreads();
  }
  // epilogue: C/D row=quad*4+reg, col=l16 ; store bf16
  #pragma unroll
  for (int g = 0; g < 2; ++g) {
    #pragma unroll
    for (int nt = 0; nt < 16; ++nt) {
      #pragma unroll
      for (int rr = 0; rr < 4; ++rr) {
        int row = row0 + wave * 32 + g * 16 + quad * 4 + rr;
        if (row < M_NODES) {
          H[(size_t)row * N_OUT + nt * 16 + l16] = f2bf_u(tanhf(acc[g][nt][rr]));
        }
      }
    }
  }
}

// y[i,:] = sum_e vals[e]*x[col[e],:], x bf16 [M,256]. One wave/row.
// Edge cols/vals preloaded by lanes, broadcast via readlane (SGPR base addr),
// gathers unrolled x4 for MLP.
template <typename OutT>
__global__ __launch_bounds__(256) void spmm_kernel_t(
    const int* __restrict__ rp, const int* __restrict__ colv,
    const float* __restrict__ vals, const unsigned short* __restrict__ x,
    OutT* __restrict__ y) {
  int w = (blockIdx.x * 256 + threadIdx.x) >> 6;
  int lane = threadIdx.x & 63;
  int i = __builtin_amdgcn_readfirstlane(w);
  int s = rp[i], e = rp[i + 1];
  float a0 = 0.f, a1 = 0.f, a2 = 0.f, a3 = 0.f;
  for (int base = s; base < e; base += 64) {
    int t = base + lane;
    int cl = 0; unsigned vl = 0;
    if (t < e) { cl = colv[t]; vl = __builtin_bit_cast(unsigned, vals[t]); }
    int cnt = min(64, e - base);
    int j = 0;
    for (; j + 4 <= cnt; j += 4) {
      int c0 = __builtin_amdgcn_readlane(cl, j);
      int c1 = __builtin_amdgcn_readlane(cl, j + 1);
      int c2 = __builtin_amdgcn_readlane(cl, j + 2);
      int c3 = __builtin_amdgcn_readlane(cl, j + 3);
      float v0 = __builtin_bit_cast(float, __builtin_amdgcn_readlane(vl, j));
      float v1 = __builtin_bit_cast(float, __builtin_amdgcn_readlane(vl, j + 1));
      float v2 = __builtin_bit_cast(float, __builtin_amdgcn_readlane(vl, j + 2));
      float v3 = __builtin_bit_cast(float, __builtin_amdgcn_readlane(vl, j + 3));
      ushort4 x0 = *(const ushort4*)(x + (size_t)c0 * N_OUT + lane * 4);
      ushort4 x1 = *(const ushort4*)(x + (size_t)c1 * N_OUT + lane * 4);
      ushort4 x2 = *(const ushort4*)(x + (size_t)c2 * N_OUT + lane * 4);
      ushort4 x3 = *(const ushort4*)(x + (size_t)c3 * N_OUT + lane * 4);
      a0 += v0 * bfu2f(x0.x); a1 += v0 * bfu2f(x0.y);
      a2 += v0 * bfu2f(x0.z); a3 += v0 * bfu2f(x0.w);
      a0 += v1 * bfu2f(x1.x); a1 += v1 * bfu2f(x1.y);
      a2 += v1 * bfu2f(x1.z); a3 += v1 * bfu2f(x1.w);
      a0 += v2 * bfu2f(x2.x); a1 += v2 * bfu2f(x2.y);
      a2 += v2 * bfu2f(x2.z); a3 += v2 * bfu2f(x2.w);
      a0 += v3 * bfu2f(x3.x); a1 += v3 * bfu2f(x3.y);
      a2 += v3 * bfu2f(x3.z); a3 += v3 * bfu2f(x3.w);
    }
    for (; j < cnt; ++j) {
      int c = __builtin_amdgcn_readlane(cl, j);
      float v = __builtin_bit_cast(float, __builtin_amdgcn_readlane(vl, j));
      ushort4 xv = *(const ushort4*)(x + (size_t)c * N_OUT + lane * 4);
      a0 += v * bfu2f(xv.x); a1 += v * bfu2f(xv.y);
      a2 += v * bfu2f(xv.z); a3 += v * bfu2f(xv.w);
    }
  }
  if constexpr (sizeof(OutT) == 2) {
    ushort4 o;
    o.x = f2bf_u(a0); o.y = f2bf_u(a1); o.z = f2bf_u(a2); o.w = f2bf_u(a3);
    *(ushort4*)((unsigned short*)y + (size_t)i * N_OUT + lane * 4) = o;
  } else {
    float4 o = {a0, a1, a2, a3};
    *(float4*)((float*)y + (size_t)i * N_OUT + lane * 4) = o;
  }
}

extern "C" void kernel_launch(void* const* d_in, const int* in_sizes, int n_in,
                              void* d_out, int out_size, void* d_ws, size_t ws_size,
                              hipStream_t stream) {
  const float* features = (const float*)d_in[0];
  const float* weight   = (const float*)d_in[1];
  const int*   row      = (const int*)d_in[2];
  const int*   col      = (const int*)d_in[3];
  const float* vals     = (const float*)d_in[4];
  float* out = (float*)d_out;

  char* ws = (char*)d_ws;
  const size_t HB = (size_t)M_NODES * N_OUT * 2;   // 51,200,000 bf16
  const size_t RPB = 400016;                        // 100001 ints padded
  unsigned short* H  = (unsigned short*)ws;
  unsigned short* y1 = (unsigned short*)(ws + HB);
  int*   rp = (int*)(ws + 2 * HB);
  short* Wt = (short*)(ws + 2 * HB + RPB);
  // total: 2*51.2MB + 400016 + 262144 = 103,062,160 B (fits: round-1 layout proved it)

  prep_w_kernel<<<512, 256, 0, stream>>>(weight, Wt);
  build_rp_kernel<<<(M_NODES + 1 + 255) / 256, 256, 0, stream>>>(row, rp);
  gemm_tanh_kernel<<<(M_NODES + 127) / 128, 256, 0, stream>>>(features, Wt, H);
  spmm_kernel_t<unsigned short><<<25000, 256, 0, stream>>>(rp, col, vals, H, y1);
  spmm_kernel_t<float><<<25000, 256, 0, stream>>>(rp, col, vals, y1, out);
}